// Round 2
// baseline (61.880 us; speedup 1.0000x reference)
//
#include <hip/hip_runtime.h>

// EquivariantProductBasisBlock (MACE symmetric contraction, nu=3) on gfx950.
//
// y = sum_t sum_p w_t[p,c] * T_t[m,p],  T3[m,p] = sum_{i<=j<=k} S3[ijk,m,p] x_i x_j x_k
// Symmetrized coefficient tables (165/45/9 monomials, 9.5 KB) built on device.
// Main kernel: coefficients are WAVE-UNIFORM -> read from global at
// compile-time-constant offsets so the backend emits s_load into SGPRs
// (v_fmac_f32 v,s,v). No LDS in the main loop; LDS only for the 2 KB
// y-exchange feeding the fused Wlin epilogue. 1 node per 128-thread block.

#define K9 9
#define NC 128
#define NE 10
#define NCOL3 12                      // L0: p=0..2 | L1: 3 + m*3 + p
#define NCOL2 8                       // L0: p=0..1 | L1: 2 + m*2 + p
#define NCOL1 4                       // L0: 0      | L1: 1 + m
#define NS3 165
#define NS2 45
#define OFF_C2 (NS3*NCOL3)            // 1980 floats
#define OFF_C1 (OFF_C2 + NS2*NCOL2)   // 2340 floats
#define TBL_FLOATS (OFF_C1 + K9*NCOL1) // 2376 floats = 9504 B

__global__ void build_tables_kernel(
    const float* __restrict__ U1_0, const float* __restrict__ U2_0, const float* __restrict__ U3_0,
    const float* __restrict__ U1_1, const float* __restrict__ U2_1, const float* __restrict__ U3_1,
    float* __restrict__ tbl)
{
  int t = threadIdx.x;
  if (t < NS3) {
    int I = 0, J = 0, Kk = 0, s = 0;
    for (int i = 0; i < K9; ++i)
      for (int j = i; j < K9; ++j)
        for (int k = j; k < K9; ++k) {
          if (s == t) { I = i; J = j; Kk = k; }
          ++s;
        }
    float col[NCOL3];
    for (int q = 0; q < NCOL3; ++q) col[q] = 0.f;
    int pm[6][3] = {{I,J,Kk},{I,Kk,J},{J,I,Kk},{J,Kk,I},{Kk,I,J},{Kk,J,I}};
    for (int p = 0; p < 6; ++p) {
      bool dup = false;
      for (int q = 0; q < p; ++q)
        if (pm[q][0]==pm[p][0] && pm[q][1]==pm[p][1] && pm[q][2]==pm[p][2]) dup = true;
      if (dup) continue;
      int base = (pm[p][0]*K9 + pm[p][1])*K9 + pm[p][2];
      for (int p3 = 0; p3 < 3; ++p3) col[p3] += U3_0[base*3 + p3];
      for (int m = 0; m < 3; ++m)
        for (int p3 = 0; p3 < 3; ++p3) col[3 + m*3 + p3] += U3_1[base*9 + m*3 + p3];
    }
    for (int q = 0; q < NCOL3; ++q) tbl[t*NCOL3 + q] = col[q];
  } else if (t < NS3 + NS2) {
    int s2 = t - NS3;
    int I = 0, J = 0, s = 0;
    for (int i = 0; i < K9; ++i)
      for (int j = i; j < K9; ++j) { if (s == s2) { I = i; J = j; } ++s; }
    float col[NCOL2];
    for (int q = 0; q < NCOL2; ++q) col[q] = 0.f;
    int pm2[2][2] = {{I,J},{J,I}};
    int np = (I == J) ? 1 : 2;
    for (int p = 0; p < np; ++p) {
      int base = pm2[p][0]*K9 + pm2[p][1];
      for (int p2 = 0; p2 < 2; ++p2) col[p2] += U2_0[base*2 + p2];
      for (int m = 0; m < 3; ++m)
        for (int p2 = 0; p2 < 2; ++p2) col[2 + m*2 + p2] += U2_1[(base*3 + m)*2 + p2];
    }
    for (int q = 0; q < NCOL2; ++q) tbl[OFF_C2 + s2*NCOL2 + q] = col[q];
  } else if (t < NS3 + NS2 + K9) {
    int i = t - NS3 - NS2;
    tbl[OFF_C1 + i*NCOL1 + 0] = U1_0[i];
    for (int m = 0; m < 3; ++m) tbl[OFF_C1 + i*NCOL1 + 1 + m] = U1_1[i*3 + m];
  }
}

__global__ __launch_bounds__(128) void epbb_main_kernel(
    const float* __restrict__ xg,    // [N,128,9]
    const float* __restrict__ na,    // [N,10] one-hot
    const float* __restrict__ sc,    // [N,512]
    const float* __restrict__ W1_0, const float* __restrict__ W2_0, const float* __restrict__ W3_0,
    const float* __restrict__ Wlin0,
    const float* __restrict__ W1_1, const float* __restrict__ W2_1, const float* __restrict__ W3_1,
    const float* __restrict__ Wlin1,
    const float* __restrict__ tbl,   // uniform coefficient table (scalar loads)
    float* __restrict__ out)         // [N,512]
{
  __shared__ __align__(16) float ly[NC*4];   // y[c][m] exchange, 2 KB

  const int c = threadIdx.x;       // channel 0..127
  const int n = blockIdx.x;        // node

  // node features for this (n,c)
  const float* xp = xg + ((long)n*NC + c)*K9;
  float xr[K9];
  #pragma unroll
  for (int k = 0; k < K9; ++k) xr[k] = xp[k];

  // species (exact one-hot)
  int e = 0;
  const float* nap = na + n*NE;
  #pragma unroll
  for (int q = 0; q < NE; ++q) e = (nap[q] > 0.5f) ? q : e;

  // per-(element, channel) path weights  W_t: (E, P_t, C)
  const float w10  = W1_0[e*NC + c];
  const float w20a = W2_0[(e*2+0)*NC + c], w20b = W2_0[(e*2+1)*NC + c];
  const float w30a = W3_0[(e*3+0)*NC + c], w30b = W3_0[(e*3+1)*NC + c], w30c = W3_0[(e*3+2)*NC + c];
  const float w11  = W1_1[e*NC + c];
  const float w21a = W2_1[(e*2+0)*NC + c], w21b = W2_1[(e*2+1)*NC + c];
  const float w31a = W3_1[(e*3+0)*NC + c], w31b = W3_1[(e*3+1)*NC + c], w31c = W3_1[(e*3+2)*NC + c];

  // Coefficients: wave-uniform compile-time offsets -> s_load (SGPR operands)
  const float4* C3v = (const float4*)tbl;              // NS3 rows x 3 float4
  const float4* C2v = (const float4*)(tbl + OFF_C2);   // NS2 rows x 2 float4
  const float4* C1v = (const float4*)(tbl + OFF_C1);   // K9  rows x 1 float4

  float a3[NCOL3], a2[NCOL2], a1[NCOL1];
  #pragma unroll
  for (int q = 0; q < NCOL3; ++q) a3[q] = 0.f;
  #pragma unroll
  for (int q = 0; q < NCOL2; ++q) a2[q] = 0.f;
  #pragma unroll
  for (int q = 0; q < NCOL1; ++q) a1[q] = 0.f;

  int s3 = 0, s2 = 0;
  #pragma unroll
  for (int i = 0; i < K9; ++i) {
    const float xi = xr[i];
    float4 c1 = C1v[i];
    a1[0] += c1.x*xi; a1[1] += c1.y*xi; a1[2] += c1.z*xi; a1[3] += c1.w*xi;
    #pragma unroll
    for (int j = i; j < K9; ++j) {
      const float pij = xi * xr[j];
      float4 b0 = C2v[s2*2+0], b1 = C2v[s2*2+1];
      a2[0] += b0.x*pij; a2[1] += b0.y*pij; a2[2] += b0.z*pij; a2[3] += b0.w*pij;
      a2[4] += b1.x*pij; a2[5] += b1.y*pij; a2[6] += b1.z*pij; a2[7] += b1.w*pij;
      ++s2;
      #pragma unroll
      for (int k = j; k < K9; ++k) {
        const float pijk = pij * xr[k];
        float4 u0 = C3v[s3*3+0], u1 = C3v[s3*3+1], u2 = C3v[s3*3+2];
        a3[0] += u0.x*pijk; a3[1]  += u0.y*pijk; a3[2]  += u0.z*pijk; a3[3]  += u0.w*pijk;
        a3[4] += u1.x*pijk; a3[5]  += u1.y*pijk; a3[6]  += u1.z*pijk; a3[7]  += u1.w*pijk;
        a3[8] += u2.x*pijk; a3[9]  += u2.y*pijk; a3[10] += u2.z*pijk; a3[11] += u2.w*pijk;
        ++s3;
      }
    }
  }

  // y[c,m]: combine path sums with per-element weights
  const float y0   = w10*a1[0] + w20a*a2[0] + w20b*a2[1] + w30a*a3[0]  + w30b*a3[1]  + w30c*a3[2];
  const float y1m0 = w11*a1[1] + w21a*a2[2] + w21b*a2[3] + w31a*a3[3]  + w31b*a3[4]  + w31c*a3[5];
  const float y1m1 = w11*a1[2] + w21a*a2[4] + w21b*a2[5] + w31a*a3[6]  + w31b*a3[7]  + w31c*a3[8];
  const float y1m2 = w11*a1[3] + w21a*a2[6] + w21b*a2[7] + w31a*a3[9]  + w31b*a3[10] + w31c*a3[11];

  ((float4*)ly)[c] = make_float4(y0, y1m0, y1m1, y1m2);
  __syncthreads();

  // fused linear epilogue: thread -> d=c; z[n,d,m] = inv * sum_c y[n,c,m] Wlin[c,d]
  const int d = c;
  float z0 = 0.f, za = 0.f, zb = 0.f, zc = 0.f;
  const float4* yrow = (const float4*)ly;
  #pragma unroll 4
  for (int cc = 0; cc < NC; ++cc) {
    float4 yv = yrow[cc];                 // LDS broadcast (wave-uniform addr)
    float wl0 = Wlin0[cc*NC + d];         // coalesced across lanes
    float wl1 = Wlin1[cc*NC + d];
    z0 += yv.x*wl0; za += yv.y*wl1; zb += yv.z*wl1; zc += yv.w*wl1;
  }
  const float inv = 0.088388347648318447f;   // 1/sqrt(128)
  const long orow = (long)n*512;
  out[orow + d]           = z0*inv + sc[orow + d];
  out[orow + 128 + 3*d+0] = za*inv + sc[orow + 128 + 3*d+0];
  out[orow + 128 + 3*d+1] = zb*inv + sc[orow + 128 + 3*d+1];
  out[orow + 128 + 3*d+2] = zc*inv + sc[orow + 128 + 3*d+2];
}

extern "C" void kernel_launch(void* const* d_in, const int* in_sizes, int n_in,
                              void* d_out, int out_size, void* d_ws, size_t ws_size,
                              hipStream_t stream) {
  const float* xg   = (const float*)d_in[0];   // node_feats [N,128,9]
  const float* na   = (const float*)d_in[1];   // node_attrs [N,10]
  const float* sc   = (const float*)d_in[2];   // sc [N,512]
  const float* U1_0 = (const float*)d_in[3];
  const float* W1_0 = (const float*)d_in[4];
  const float* U2_0 = (const float*)d_in[5];
  const float* W2_0 = (const float*)d_in[6];
  const float* U3_0 = (const float*)d_in[7];
  const float* W3_0 = (const float*)d_in[8];
  const float* Wl0  = (const float*)d_in[9];
  const float* U1_1 = (const float*)d_in[10];
  const float* W1_1 = (const float*)d_in[11];
  const float* U2_1 = (const float*)d_in[12];
  const float* W2_1 = (const float*)d_in[13];
  const float* U3_1 = (const float*)d_in[14];
  const float* W3_1 = (const float*)d_in[15];
  const float* Wl1  = (const float*)d_in[16];

  float* tbl = (float*)d_ws;                   // 9504 B of workspace
  const int N = in_sizes[0] / (NC * K9);

  hipLaunchKernelGGL(build_tables_kernel, dim3(1), dim3(256), 0, stream,
                     U1_0, U2_0, U3_0, U1_1, U2_1, U3_1, tbl);
  hipLaunchKernelGGL(epbb_main_kernel, dim3(N), dim3(NC), 0, stream,
                     xg, na, sc, W1_0, W2_0, W3_0, Wl0, W1_1, W2_1, W3_1, Wl1, tbl,
                     (float*)d_out);
}

// Round 3
// 29.618 us; speedup vs baseline: 2.0892x; 2.0892x over previous
//
#include <hip/hip_runtime.h>

// EquivariantProductBasisBlock (MACE symmetric contraction, nu=3) on gfx950.
//
// Reformulated as GEMM: Y[N*C x 24] = Mono[N*C x 224] * Coef[224 x 24]
//   k-order: k<165 order-3 multisets (i<=j<=k lex), 165..209 order-2,
//            210..218 order-1, 219..223 zero pad.
//   cols: 0..3 = t1 (m'), 4..11 = t2 (4+2m'+p), 12..23 = t3 (12+3m'+p);
//         m'=0 -> L0, m'=1..3 -> L1 m=0..2. cols 24..31 zero pad.
// Coef is built on-device directly in mfma_f32_32x32x16_bf16 B-fragment
// layout (14 K-steps x 64 lanes x 4 dwords, bf16 pairs). Monomials are
// generated per-lane in registers from x[9] and packed to bf16 A-frags.
// Epilogue: acc -> LDS, apply per-element path weights, fused Wlin (f32 VALU).
// Block = 512 threads = 8 waves = 2 nodes (256 rows).

typedef __attribute__((ext_vector_type(8))) short short8;
typedef __attribute__((ext_vector_type(16))) float f32x16;

#define NSTEP 14
#define TBLB_DWORDS (NSTEP*64*4)   // 3584 dwords = 14336 B

static __device__ __forceinline__ short bf16b(float f) {
  __bf16 h = (__bf16)f;
  return __builtin_bit_cast(short, h);
}

// ---- compile-time monomial index table (lex order, matches build kernel) ----
struct Triples { unsigned char a[224], b[224], c3[224], ord[224]; };
constexpr Triples make_triples() {
  Triples T{};
  int s = 0;
  for (int i = 0; i < 9; ++i)
    for (int j = i; j < 9; ++j)
      for (int k = j; k < 9; ++k) { T.a[s]=(unsigned char)i; T.b[s]=(unsigned char)j; T.c3[s]=(unsigned char)k; T.ord[s]=3; ++s; }
  for (int i = 0; i < 9; ++i)
    for (int j = i; j < 9; ++j) { T.a[s]=(unsigned char)i; T.b[s]=(unsigned char)j; T.ord[s]=2; ++s; }
  for (int i = 0; i < 9; ++i) { T.a[s]=(unsigned char)i; T.ord[s]=1; ++s; }
  for (; s < 224; ++s) T.ord[s] = 0;
  return T;
}
static constexpr Triples TRI = make_triples();

template<int KI>
static __device__ __forceinline__ float monoT(const float* xr) {
  if constexpr (TRI.ord[KI] == 3) return xr[TRI.a[KI]] * xr[TRI.b[KI]] * xr[TRI.c3[KI]];
  else if constexpr (TRI.ord[KI] == 2) return xr[TRI.a[KI]] * xr[TRI.b[KI]];
  else if constexpr (TRI.ord[KI] == 1) return xr[TRI.a[KI]];
  else return 0.f;
}

template<int K0>
static __device__ __forceinline__ void mono8(const float* xr, float m[8]) {
  m[0]=monoT<K0+0>(xr); m[1]=monoT<K0+1>(xr); m[2]=monoT<K0+2>(xr); m[3]=monoT<K0+3>(xr);
  m[4]=monoT<K0+4>(xr); m[5]=monoT<K0+5>(xr); m[6]=monoT<K0+6>(xr); m[7]=monoT<K0+7>(xr);
}

template<int T>
static __device__ __forceinline__ void k_steps(const float* xr, const unsigned int* lds_b,
                                               int lane, int ks, f32x16& acc) {
  if constexpr (T < NSTEP) {
    float m[8];
    if (ks == 0) mono8<T*16>(xr, m);
    else         mono8<T*16 + 8>(xr, m);
    short8 af;
    af[0]=bf16b(m[0]); af[1]=bf16b(m[1]); af[2]=bf16b(m[2]); af[3]=bf16b(m[3]);
    af[4]=bf16b(m[4]); af[5]=bf16b(m[5]); af[6]=bf16b(m[6]); af[7]=bf16b(m[7]);
    short8 bf = *(const short8*)&lds_b[(T*64 + lane)*4];
    acc = __builtin_amdgcn_mfma_f32_32x32x16_bf16(af, bf, acc, 0, 0, 0);
    k_steps<T+1>(xr, lds_b, lane, ks, acc);
  }
}

// ---- build kernel: Coef in B-fragment layout, bf16-packed ----
static __device__ __forceinline__ float coefval(int k, int col,
    const float* U1_0, const float* U2_0, const float* U3_0,
    const float* U1_1, const float* U2_1, const float* U3_1) {
  if (k < 165) {
    if (col < 12 || col >= 24) return 0.f;
    int mp = (col - 12) / 3, p = (col - 12) % 3;
    int rem = k, I = 0;
    while (rem >= (9 - I) * (10 - I) / 2) { rem -= (9 - I) * (10 - I) / 2; ++I; }
    int J = I;
    while (rem >= 9 - J) { rem -= 9 - J; ++J; }
    int Kk = J + rem;
    int pm[6][3] = {{I,J,Kk},{I,Kk,J},{J,I,Kk},{J,Kk,I},{Kk,I,J},{Kk,J,I}};
    float acc = 0.f;
    for (int q = 0; q < 6; ++q) {
      bool dup = false;
      for (int r = 0; r < q; ++r)
        if (pm[r][0]==pm[q][0] && pm[r][1]==pm[q][1] && pm[r][2]==pm[q][2]) dup = true;
      if (dup) continue;
      int base = (pm[q][0]*9 + pm[q][1])*9 + pm[q][2];
      acc += (mp == 0) ? U3_0[base*3 + p] : U3_1[base*9 + (mp-1)*3 + p];
    }
    return acc;
  } else if (k < 210) {
    if (col < 4 || col >= 12) return 0.f;
    int mp = (col - 4) / 2, p = (col - 4) % 2;
    int rem = k - 165, I = 0;
    while (rem >= 9 - I) { rem -= 9 - I; ++I; }
    int J = I + rem;
    float acc = (mp == 0) ? U2_0[(I*9+J)*2 + p] : U2_1[((I*9+J)*3 + (mp-1))*2 + p];
    if (I != J) acc += (mp == 0) ? U2_0[(J*9+I)*2 + p] : U2_1[((J*9+I)*3 + (mp-1))*2 + p];
    return acc;
  } else if (k < 219) {
    int i = k - 210;
    if (col == 0) return U1_0[i];
    if (col < 4) return U1_1[i*3 + (col-1)];
    return 0.f;
  }
  return 0.f;
}

__global__ void build_tables_kernel(
    const float* __restrict__ U1_0, const float* __restrict__ U2_0, const float* __restrict__ U3_0,
    const float* __restrict__ U1_1, const float* __restrict__ U2_1, const float* __restrict__ U3_1,
    unsigned int* __restrict__ tblB) {
  int tid = threadIdx.x;           // 0..895
  if (tid >= NSTEP*64) return;
  int ft = tid >> 6, l = tid & 63;
  int col = l & 31, ks = l >> 5;
  #pragma unroll
  for (int d = 0; d < 4; ++d) {
    int k = ft*16 + ks*8 + d*2;
    unsigned short lo = (unsigned short)bf16b(coefval(k,   col, U1_0,U2_0,U3_0,U1_1,U2_1,U3_1));
    unsigned short hi = (unsigned short)bf16b(coefval(k+1, col, U1_0,U2_0,U3_0,U1_1,U2_1,U3_1));
    tblB[(ft*64 + l)*4 + d] = ((unsigned int)hi << 16) | lo;
  }
}

// ---- main kernel ----
__global__ __launch_bounds__(512, 4) void epbb_mfma_kernel(
    const float* __restrict__ xg,    // [N,128,9]
    const float* __restrict__ na,    // [N,10] one-hot
    const float* __restrict__ sc,    // [N,512]
    const float* __restrict__ W1_0, const float* __restrict__ W2_0, const float* __restrict__ W3_0,
    const float* __restrict__ Wlin0,
    const float* __restrict__ W1_1, const float* __restrict__ W2_1, const float* __restrict__ W3_1,
    const float* __restrict__ Wlin1,
    const unsigned int* __restrict__ tblB,
    float* __restrict__ out) {
  __shared__ __align__(16) unsigned int lds_b[TBLB_DWORDS];  // 14336 B
  __shared__ __align__(16) float lds_acc[8*32*33];           // 33792 B
  __shared__ __align__(16) float lds_y[128*2*4];             // 4096 B

  const int tid  = threadIdx.x;
  const int lane = tid & 63;
  const int w    = tid >> 6;          // wave 0..7
  const int n0   = blockIdx.x * 2;

  // stage coefficient B-frags to LDS (coalesced)
  for (int q = tid; q < TBLB_DWORDS; q += 512) lds_b[q] = tblB[q];

  // species for both nodes (exact one-hot)
  int e0 = 0, e1 = 0;
  #pragma unroll
  for (int q = 0; q < 10; ++q) {
    e0 = (na[(long)n0*10 + q]       > 0.5f) ? q : e0;
    e1 = (na[(long)(n0+1)*10 + q]   > 0.5f) ? q : e1;
  }

  // this wave's 32 rows: node n, channels c0..c0+31; lane owns row c0+(lane&31)
  const int n  = n0 + (w >> 2);
  const int c0 = (w & 3) * 32;
  const float* xp = xg + ((long)(n*128 + c0 + (lane & 31)))*9;
  float xr[9];
  #pragma unroll
  for (int q = 0; q < 9; ++q) xr[q] = xp[q];

  f32x16 acc;
  #pragma unroll
  for (int q = 0; q < 16; ++q) acc[q] = 0.f;

  __syncthreads();   // lds_b ready

  const int ks = lane >> 5;
  k_steps<0>(xr, lds_b, lane, ks, acc);

  // dump acc to LDS: C/D layout col=lane&31, row=(reg&3)+8*(reg>>2)+4*(lane>>5)
  {
    float* ab = lds_acc + (w * 32) * 33;
    #pragma unroll
    for (int r = 0; r < 16; ++r) {
      int rr = (r & 3) + 8*(r >> 2) + 4*ks;
      ab[rr*33 + (lane & 31)] = acc[r];
    }
  }
  __syncthreads();

  // phase 2: y[row,m'] = sum over path columns with per-element weights
  #pragma unroll
  for (int rep = 0; rep < 2; ++rep) {
    int q = tid + rep*512;           // 1024 items = 256 rows x 4 m'
    int row_b = q >> 2, mp = q & 3;
    int nv = row_b >> 7, cl = row_b & 127;
    int e = nv ? e1 : e0;
    const float* abp = lds_acc + row_b*33;
    const float* w1 = mp ? W1_1 : W1_0;
    const float* w2 = mp ? W2_1 : W2_0;
    const float* w3 = mp ? W3_1 : W3_0;
    float y = w1[e*128 + cl] * abp[mp]
            + w2[(e*2+0)*128 + cl] * abp[4 + 2*mp] + w2[(e*2+1)*128 + cl] * abp[5 + 2*mp]
            + w3[(e*3+0)*128 + cl] * abp[12 + 3*mp] + w3[(e*3+1)*128 + cl] * abp[13 + 3*mp]
            + w3[(e*3+2)*128 + cl] * abp[14 + 3*mp];
    lds_y[(cl*2 + nv)*4 + mp] = y;
  }
  __syncthreads();

  // phase 3: fused Wlin + sc + store (f32 VALU). thread <-> (nv, d)
  if (tid < 256) {
    int nv = tid >> 7, d = tid & 127;
    float z0 = 0.f, z1 = 0.f, z2 = 0.f, z3 = 0.f;
    const float4* yb = (const float4*)lds_y;
    #pragma unroll 4
    for (int cc = 0; cc < 128; ++cc) {
      float4 y4 = yb[cc*2 + nv];          // LDS broadcast
      float a = Wlin0[cc*128 + d];        // coalesced
      float b = Wlin1[cc*128 + d];
      z0 += y4.x*a; z1 += y4.y*b; z2 += y4.z*b; z3 += y4.w*b;
    }
    const float inv = 0.088388347648318447f;   // 1/sqrt(128)
    long o = (long)(n0 + nv) * 512;
    out[o + d]             = z0*inv + sc[o + d];
    out[o + 128 + 3*d + 0] = z1*inv + sc[o + 128 + 3*d + 0];
    out[o + 128 + 3*d + 1] = z2*inv + sc[o + 128 + 3*d + 1];
    out[o + 128 + 3*d + 2] = z3*inv + sc[o + 128 + 3*d + 2];
  }
}

extern "C" void kernel_launch(void* const* d_in, const int* in_sizes, int n_in,
                              void* d_out, int out_size, void* d_ws, size_t ws_size,
                              hipStream_t stream) {
  const float* xg   = (const float*)d_in[0];   // node_feats [N,128,9]
  const float* na   = (const float*)d_in[1];   // node_attrs [N,10]
  const float* sc   = (const float*)d_in[2];   // sc [N,512]
  const float* U1_0 = (const float*)d_in[3];
  const float* W1_0 = (const float*)d_in[4];
  const float* U2_0 = (const float*)d_in[5];
  const float* W2_0 = (const float*)d_in[6];
  const float* U3_0 = (const float*)d_in[7];
  const float* W3_0 = (const float*)d_in[8];
  const float* Wl0  = (const float*)d_in[9];
  const float* U1_1 = (const float*)d_in[10];
  const float* W1_1 = (const float*)d_in[11];
  const float* U2_1 = (const float*)d_in[12];
  const float* W2_1 = (const float*)d_in[13];
  const float* U3_1 = (const float*)d_in[14];
  const float* W3_1 = (const float*)d_in[15];
  const float* Wl1  = (const float*)d_in[16];

  unsigned int* tblB = (unsigned int*)d_ws;    // 14336 B of workspace
  const int N = in_sizes[0] / (128 * 9);

  hipLaunchKernelGGL(build_tables_kernel, dim3(1), dim3(NSTEP*64), 0, stream,
                     U1_0, U2_0, U3_0, U1_1, U2_1, U3_1, tblB);
  hipLaunchKernelGGL(epbb_mfma_kernel, dim3(N/2), dim3(512), 0, stream,
                     xg, na, sc, W1_0, W2_0, W3_0, Wl0, W1_1, W2_1, W3_1, Wl1, tblB,
                     (float*)d_out);
}

// Round 5
// 23.555 us; speedup vs baseline: 2.6270x; 1.2574x over previous
//
#include <hip/hip_runtime.h>

// EquivariantProductBasisBlock (MACE symmetric contraction, nu=3) on gfx950.
//
// GEMM form: D[pc x ch] = Coef^T * Mono^T via mfma(coef_frag, mono_frag):
//   lane holds channel = lane&31, path-cols rr=(r&3)+8*(r>>2)+4*ks across regs.
//   (R3 established D[row][col] = [afdim][bfdim], col=lane&31, row=rr.)
// Phase 2: per-element path weights applied IN-REGISTER on the accumulator,
//          halves combined with one shfl_xor(32) per m'.
// Phase 3: z = y * Wlin as two padded MFMA GEMMs (rows 2 and 6 of 32), Wlin
//          pre-packed to bf16 B-fragments in d_ws by the build kernel.
// Build kernel parallelized: 78 blocks x 64 threads.

typedef __attribute__((ext_vector_type(8))) short short8;
typedef __attribute__((ext_vector_type(16))) float f32x16;

#define NSTEP 14
#define TBLB_DWORDS (NSTEP*64*4)    // 3584 dwords: Coef frags (A-side)
#define WL_OFF TBLB_DWORDS
#define TBLW_DWORDS (64*256)        // 16384 dwords: Wlin B-frags

static __device__ __forceinline__ short bf16b(float f) {
  __bf16 h = (__bf16)f;
  return __builtin_bit_cast(short, h);
}

// ---- compile-time monomial index table (lex order, matches build kernel) ----
struct Triples { unsigned char a[224], b[224], c3[224], ord[224]; };
constexpr Triples make_triples() {
  Triples T{};
  int s = 0;
  for (int i = 0; i < 9; ++i)
    for (int j = i; j < 9; ++j)
      for (int k = j; k < 9; ++k) { T.a[s]=(unsigned char)i; T.b[s]=(unsigned char)j; T.c3[s]=(unsigned char)k; T.ord[s]=3; ++s; }
  for (int i = 0; i < 9; ++i)
    for (int j = i; j < 9; ++j) { T.a[s]=(unsigned char)i; T.b[s]=(unsigned char)j; T.ord[s]=2; ++s; }
  for (int i = 0; i < 9; ++i) { T.a[s]=(unsigned char)i; T.ord[s]=1; ++s; }
  for (; s < 224; ++s) T.ord[s] = 0;
  return T;
}
static constexpr Triples TRI = make_triples();

template<int KI>
static __device__ __forceinline__ float monoT(const float* xr) {
  if constexpr (TRI.ord[KI] == 3) return xr[TRI.a[KI]] * xr[TRI.b[KI]] * xr[TRI.c3[KI]];
  else if constexpr (TRI.ord[KI] == 2) return xr[TRI.a[KI]] * xr[TRI.b[KI]];
  else if constexpr (TRI.ord[KI] == 1) return xr[TRI.a[KI]];
  else return 0.f;
}

template<int K0>
static __device__ __forceinline__ void mono8(const float* xr, float m[8]) {
  m[0]=monoT<K0+0>(xr); m[1]=monoT<K0+1>(xr); m[2]=monoT<K0+2>(xr); m[3]=monoT<K0+3>(xr);
  m[4]=monoT<K0+4>(xr); m[5]=monoT<K0+5>(xr); m[6]=monoT<K0+6>(xr); m[7]=monoT<K0+7>(xr);
}

template<int T>
static __device__ __forceinline__ void k_steps(const float* xr, const unsigned int* lds_b,
                                               int lane, int ks, f32x16& acc) {
  if constexpr (T < NSTEP) {
    float m[8];
    if (ks == 0) mono8<T*16>(xr, m);
    else         mono8<T*16 + 8>(xr, m);
    short8 mf;
    mf[0]=bf16b(m[0]); mf[1]=bf16b(m[1]); mf[2]=bf16b(m[2]); mf[3]=bf16b(m[3]);
    mf[4]=bf16b(m[4]); mf[5]=bf16b(m[5]); mf[6]=bf16b(m[6]); mf[7]=bf16b(m[7]);
    short8 cf = *(const short8*)&lds_b[(T*64 + lane)*4];
    // A = Coef^T (rows = path-cols), B = Mono^T (cols = channels):
    // lane ends up holding its CHANNEL's path-cols across regs.
    acc = __builtin_amdgcn_mfma_f32_32x32x16_bf16(cf, mf, acc, 0, 0, 0);
    k_steps<T+1>(xr, lds_b, lane, ks, acc);
  }
}

// ---- build kernel helpers ----
static __device__ __forceinline__ float coefval(int k, int col,
    const float* U1_0, const float* U2_0, const float* U3_0,
    const float* U1_1, const float* U2_1, const float* U3_1) {
  if (k < 165) {
    if (col < 12 || col >= 24) return 0.f;
    int mp = (col - 12) / 3, p = (col - 12) % 3;
    int rem = k, I = 0;
    while (rem >= (9 - I) * (10 - I) / 2) { rem -= (9 - I) * (10 - I) / 2; ++I; }
    int J = I;
    while (rem >= 9 - J) { rem -= 9 - J; ++J; }
    int Kk = J + rem;
    int pm[6][3] = {{I,J,Kk},{I,Kk,J},{J,I,Kk},{J,Kk,I},{Kk,I,J},{Kk,J,I}};
    float acc = 0.f;
    for (int q = 0; q < 6; ++q) {
      bool dup = false;
      for (int r = 0; r < q; ++r)
        if (pm[r][0]==pm[q][0] && pm[r][1]==pm[q][1] && pm[r][2]==pm[q][2]) dup = true;
      if (dup) continue;
      int base = (pm[q][0]*9 + pm[q][1])*9 + pm[q][2];
      acc += (mp == 0) ? U3_0[base*3 + p] : U3_1[base*9 + (mp-1)*3 + p];
    }
    return acc;
  } else if (k < 210) {
    if (col < 4 || col >= 12) return 0.f;
    int mp = (col - 4) / 2, p = (col - 4) % 2;
    int rem = k - 165, I = 0;
    while (rem >= 9 - I) { rem -= 9 - I; ++I; }
    int J = I + rem;
    float acc = (mp == 0) ? U2_0[(I*9+J)*2 + p] : U2_1[((I*9+J)*3 + (mp-1))*2 + p];
    if (I != J) acc += (mp == 0) ? U2_0[(J*9+I)*2 + p] : U2_1[((J*9+I)*3 + (mp-1))*2 + p];
    return acc;
  } else if (k < 219) {
    int i = k - 210;
    if (col == 0) return U1_0[i];
    if (col < 4) return U1_1[i*3 + (col-1)];
    return 0.f;
  }
  return 0.f;
}

__global__ __launch_bounds__(64) void build_tables_kernel(
    const float* __restrict__ U1_0, const float* __restrict__ U2_0, const float* __restrict__ U3_0,
    const float* __restrict__ U1_1, const float* __restrict__ U2_1, const float* __restrict__ U3_1,
    const float* __restrict__ Wl0, const float* __restrict__ Wl1,
    unsigned int* __restrict__ tbl) {
  const int b = blockIdx.x, l = threadIdx.x;
  const int col = l & 31, ks = l >> 5;
  if (b < NSTEP) {
    const int ft = b;
    #pragma unroll
    for (int d = 0; d < 4; ++d) {
      int k = ft*16 + ks*8 + d*2;
      unsigned short lo = (unsigned short)bf16b(coefval(k,   col, U1_0,U2_0,U3_0,U1_1,U2_1,U3_1));
      unsigned short hi = (unsigned short)bf16b(coefval(k+1, col, U1_0,U2_0,U3_0,U1_1,U2_1,U3_1));
      tbl[(ft*64 + l)*4 + d] = ((unsigned int)hi << 16) | lo;
    }
  } else {
    const int u = b - NSTEP;            // 0..63 : (g, ntile, step)
    const int g = u >> 5, u5 = u & 31, nt = u5 >> 3, st = u5 & 7;
    const float* W = g ? Wl1 : Wl0;     // [c][d] row-major; k = c
    #pragma unroll
    for (int d = 0; d < 4; ++d) {
      int k = st*16 + ks*8 + 2*d;
      unsigned short lo = (unsigned short)bf16b(W[(long)k*128     + nt*32 + col]);
      unsigned short hi = (unsigned short)bf16b(W[(long)(k+1)*128 + nt*32 + col]);
      tbl[WL_OFF + u*256 + l*4 + d] = ((unsigned int)hi << 16) | lo;
    }
  }
}

// ---- main kernel ----
__global__ __launch_bounds__(512, 4) void epbb_mfma_kernel(
    const float* __restrict__ xg,    // [N,128,9]
    const float* __restrict__ na,    // [N,10] one-hot
    const float* __restrict__ sc,    // [N,512]
    const float* __restrict__ W1_0, const float* __restrict__ W2_0, const float* __restrict__ W3_0,
    const float* __restrict__ W1_1, const float* __restrict__ W2_1, const float* __restrict__ W3_1,
    const unsigned int* __restrict__ tbl,
    float* __restrict__ out) {
  __shared__ __align__(16) unsigned int lds_b[TBLB_DWORDS];  // 14336 B
  __shared__ __align__(16) short lds_yA[2][8][136];          // 4352 B, 272B row stride

  const int tid  = threadIdx.x;
  const int lane = tid & 63;
  const int w    = tid >> 6;          // wave 0..7
  const int ks   = lane >> 5;
  const int n0   = blockIdx.x * 2;

  for (int q = tid; q < TBLB_DWORDS; q += 512) lds_b[q] = tbl[q];

  // this wave: node nw, channels c0..c0+31; lane owns channel cl
  const int nw = w >> 2;
  const int n  = n0 + nw;
  const int c0 = (w & 3) * 32;
  const int cl = c0 + (lane & 31);
  const float* xp = xg + ((long)(n*128 + cl))*9;
  float xr[9];
  #pragma unroll
  for (int q = 0; q < 9; ++q) xr[q] = xp[q];

  // species (exact one-hot, wave-uniform)
  int e = 0;
  #pragma unroll
  for (int q = 0; q < 10; ++q) e = (na[(long)n*10 + q] > 0.5f) ? q : e;

  f32x16 acc;
  #pragma unroll
  for (int q = 0; q < 16; ++q) acc[q] = 0.f;

  __syncthreads();   // lds_b ready
  k_steps<0>(xr, lds_b, lane, ks, acc);

  // ---- phase 2: in-register weighted path reduction ----
  // D[pc][ch]: lane holds ch=lane&31, path-col rr=(r&3)+8*(r>>2)+4*ks at reg r.
  // ks=0 regs: cols {0-3, 8-11, 16-19}; ks=1 regs: cols {4-7, 12-15, 20-23}.
  const float w10  = W1_0[e*128 + cl];
  const float w20a = W2_0[(e*2+0)*128 + cl], w20b = W2_0[(e*2+1)*128 + cl];
  const float w30a = W3_0[(e*3+0)*128 + cl], w30b = W3_0[(e*3+1)*128 + cl], w30c = W3_0[(e*3+2)*128 + cl];
  const float w11  = W1_1[e*128 + cl];
  const float w21a = W2_1[(e*2+0)*128 + cl], w21b = W2_1[(e*2+1)*128 + cl];
  const float w31a = W3_1[(e*3+0)*128 + cl], w31b = W3_1[(e*3+1)*128 + cl], w31c = W3_1[(e*3+2)*128 + cl];

  float p0, p1, p2, p3;
  if (ks == 0) {
    p0 = w10*acc[0];
    p1 = w11*acc[1] + w31b*acc[8]  + w31c*acc[9];
    p2 = w11*acc[2] + w21a*acc[4]  + w21b*acc[5] + w31a*acc[10] + w31b*acc[11];
    p3 = w11*acc[3] + w21a*acc[6]  + w21b*acc[7];
  } else {
    p0 = w20a*acc[0] + w20b*acc[1] + w30a*acc[4] + w30b*acc[5] + w30c*acc[6];
    p1 = w21a*acc[2] + w21b*acc[3] + w31a*acc[7];
    p2 = w31c*acc[8];
    p3 = w31a*acc[9] + w31b*acc[10] + w31c*acc[11];
  }
  const float y0 = p0 + __shfl_xor(p0, 32, 64);
  const float y1 = p1 + __shfl_xor(p1, 32, 64);
  const float y2 = p2 + __shfl_xor(p2, 32, 64);
  const float y3 = p3 + __shfl_xor(p3, 32, 64);

  // stage y (bf16) into padded A-tile: g0 rows {nv}, g1 rows {(mp-1)*2+nv}
  if (ks == 0) {
    lds_yA[0][nw][cl]     = bf16b(y0);       // mp=0
    lds_yA[1][nw][cl]     = bf16b(y1);       // mp=1 -> row nv
  } else {
    lds_yA[1][2 + nw][cl] = bf16b(y2);       // mp=2 -> row 2+nv
    lds_yA[1][4 + nw][cl] = bf16b(y3);       // mp=3 -> row 4+nv
  }
  __syncthreads();

  // ---- phase 3: z = y * Wlin via padded MFMA (wave -> (g, ntile)) ----
  const int g  = w >> 2;
  const int nt = w & 3;
  f32x16 z;
  #pragma unroll
  for (int q = 0; q < 16; ++q) z[q] = 0.f;
  const unsigned int* bw = tbl + WL_OFF + ((g*4 + nt)*8)*256;
  #pragma unroll
  for (int st = 0; st < 8; ++st) {
    short8 af = *(const short8*)&lds_yA[g][lane & 7][st*16 + ks*8];  // rows>=8 wrap: broadcast, ignored rows
    short8 bf = *(const short8*)&bw[st*256 + lane*4];
    z = __builtin_amdgcn_mfma_f32_32x32x16_bf16(af, bf, z, 0, 0, 0);
  }
  const float inv = 0.088388347648318447f;   // 1/sqrt(128)
  const int d = nt*32 + (lane & 31);
  if (g == 0) {
    if (ks == 0) {
      #pragma unroll
      for (int r = 0; r < 2; ++r) {          // row r = nv
        long o = (long)(n0 + r)*512 + d;
        out[o] = z[r]*inv + sc[o];
      }
    }
  } else {
    if (ks == 0) {
      #pragma unroll
      for (int r = 0; r < 4; ++r) {          // rows 0..3: nv=r&1, mp-1=r>>1
        long o = (long)(n0 + (r & 1))*512 + 128 + 3*d + (r >> 1);
        out[o] = z[r]*inv + sc[o];
      }
    } else {
      #pragma unroll
      for (int r = 0; r < 2; ++r) {          // rows 4,5: nv=r, mp-1=2
        long o = (long)(n0 + r)*512 + 128 + 3*d + 2;
        out[o] = z[r]*inv + sc[o];
      }
    }
  }
}

extern "C" void kernel_launch(void* const* d_in, const int* in_sizes, int n_in,
                              void* d_out, int out_size, void* d_ws, size_t ws_size,
                              hipStream_t stream) {
  const float* xg   = (const float*)d_in[0];   // node_feats [N,128,9]
  const float* na   = (const float*)d_in[1];   // node_attrs [N,10]
  const float* sc   = (const float*)d_in[2];   // sc [N,512]
  const float* U1_0 = (const float*)d_in[3];
  const float* W1_0 = (const float*)d_in[4];
  const float* U2_0 = (const float*)d_in[5];
  const float* W2_0 = (const float*)d_in[6];
  const float* U3_0 = (const float*)d_in[7];
  const float* W3_0 = (const float*)d_in[8];
  const float* Wl0  = (const float*)d_in[9];
  const float* U1_1 = (const float*)d_in[10];
  const float* W1_1 = (const float*)d_in[11];
  const float* U2_1 = (const float*)d_in[12];
  const float* W2_1 = (const float*)d_in[13];
  const float* U3_1 = (const float*)d_in[14];
  const float* W3_1 = (const float*)d_in[15];
  const float* Wl1  = (const float*)d_in[16];

  unsigned int* tbl = (unsigned int*)d_ws;     // (3584 + 16384) dwords = 79872 B
  const int N = in_sizes[0] / (128 * 9);

  hipLaunchKernelGGL(build_tables_kernel, dim3(NSTEP + 64), dim3(64), 0, stream,
                     U1_0, U2_0, U3_0, U1_1, U2_1, U3_1, Wl0, Wl1, tbl);
  hipLaunchKernelGGL(epbb_mfma_kernel, dim3(N/2), dim3(512), 0, stream,
                     xg, na, sc, W1_0, W2_0, W3_0, W1_1, W2_1, W3_1, tbl,
                     (float*)d_out);
}